// Round 9
// baseline (159.079 us; speedup 1.0000x reference)
//
#include <hip/hip_runtime.h>
#include <hip/hip_bf16.h>

#define B_ 128
#define F_ 100
#define N_ 512
#define H_ 1024
#define P_ 512
#define E_ 8
#define BKL 128     // K-step (shorts); deeper DMA queue per stage
#define AROWS 112   // staged A rows (M=100 rounded to DMA granularity)

typedef __attribute__((ext_vector_type(8))) short bf16x8;
typedef __attribute__((ext_vector_type(4))) float f32x4;

// async global->LDS DMA, 16B/lane, LDS dest = wave-uniform base + lane*16
#define GLOAD16(g, l) __builtin_amdgcn_global_load_lds(                      \
    (const __attribute__((address_space(1))) void*)(g),                      \
    (__attribute__((address_space(3))) void*)(l), 16, 0, 0)

static __device__ __forceinline__ short f2bf(float f) {
    __hip_bfloat16 h = __float2bfloat16(f);
    short s;
    __builtin_memcpy(&s, &h, sizeof(s));
    return s;
}

// ONE prep kernel, grid sections:
//   [0,3200)      convert x [B][F][N] fp32 -> xbf [12800][N] bf16 (linear)
//   [3200,4224)   transpose W1 [E][512][1024] -> W1T [E][1024][512] bf16
//   [4224,5248)   transpose W2 [E][1024][512] -> W2T [E][512][1024] bf16
//   5248          tile table sorted by expert (data stays in trial order)
__global__ __launch_bounds__(256) void prep(
    const float* __restrict__ x, const float* __restrict__ W1,
    const float* __restrict__ W2, const int* __restrict__ eid,
    short* __restrict__ xbf, short* __restrict__ W1T, short* __restrict__ W2T,
    int2* __restrict__ ttab) {
    __shared__ float tile[64][65];
    __shared__ int scnt[E_], sbase[E_];
    const int bx = blockIdx.x;
    const int t = threadIdx.x;
    if (bx < 3200) {  // ---- convert x ----
        const int g = bx * 256 + t;
        const int col = (g & 63) * 8;
        const int row = g >> 6;  // 0..12799
        const float* xp = x + (size_t)row * N_ + col;
        const float4 v0 = *(const float4*)(xp);
        const float4 v1 = *(const float4*)(xp + 4);
        union { short s[8]; uint4 u; } o;
        o.s[0] = f2bf(v0.x); o.s[1] = f2bf(v0.y);
        o.s[2] = f2bf(v0.z); o.s[3] = f2bf(v0.w);
        o.s[4] = f2bf(v1.x); o.s[5] = f2bf(v1.y);
        o.s[6] = f2bf(v1.z); o.s[7] = f2bf(v1.w);
        *(uint4*)(xbf + (size_t)row * N_ + col) = o.u;
    } else if (bx < 5248) {  // ---- weight transpose+convert ----
        const float* W; short* WT; int R, C, r0, c0, e;
        if (bx < 4224) {
            const int idx = bx - 3200;
            e = idx >> 7; const int i = idx & 127;
            W = W1; WT = W1T; R = N_; C = H_;
            r0 = (i >> 4) * 64; c0 = (i & 15) * 64;
        } else {
            const int idx = bx - 4224;
            e = idx >> 7; const int i = idx & 127;
            W = W2; WT = W2T; R = H_; C = P_;
            r0 = (i & 15) * 64; c0 = (i >> 4) * 64;
        }
        const float* Wp = W + (size_t)e * R * C;
        short* WTp = WT + (size_t)e * C * R;
        {
            const int c4 = (t & 15) * 4, r = t >> 4;
#pragma unroll
            for (int p = 0; p < 4; p++) {
                const int row = p * 16 + r;
                const float4 v = *(const float4*)(Wp + (size_t)(r0 + row) * C + c0 + c4);
                tile[row][c4 + 0] = v.x; tile[row][c4 + 1] = v.y;
                tile[row][c4 + 2] = v.z; tile[row][c4 + 3] = v.w;
            }
        }
        __syncthreads();
        {
            const int r8 = (t & 7) * 8, cl = t >> 3;
#pragma unroll
            for (int p = 0; p < 2; p++) {
                const int c = p * 32 + cl;
                union { short s[8]; uint4 u; } o;
#pragma unroll
                for (int j = 0; j < 8; j++) o.s[j] = f2bf(tile[r8 + j][c]);
                *(uint4*)(&WTp[(size_t)(c0 + c) * R + r0 + r8]) = o.u;
            }
        }
    } else {  // ---- tile-table sort (one block) ----
        if (t < E_) scnt[t] = 0;
        __syncthreads();
        int my_e = 0;
        if (t < B_) { my_e = eid[t]; atomicAdd(&scnt[my_e], 1); }
        __syncthreads();
        if (t == 0) {
            int s = 0;
            for (int i = 0; i < E_; i++) { sbase[i] = s; s += scnt[i]; }
        }
        __syncthreads();
        if (t < B_) {
            const int pos = atomicAdd(&sbase[my_e], 1);
            ttab[pos] = make_int2(t, my_e);
        }
    }
}

// 128x128 tile GEMM, BK=128 deep-queue variant. Same bytes/occupancy/swizzle
// family as R3; the ISOLATED change is per-stage DMA queue depth: 60 DMAs
// per block per stage (A 28 + B 32; 120 KB in flight per CU at 2 blocks/CU)
// vs R3's 30, and half the barrier/drain count (K/128 steps).
// LDS (112+128)x128x2 = 60 KiB single buffer (64 KiB static cap forbids
// dbuf; R2/R3 measured drain == counted, so nothing is given up).
// Swizzle: k-chunk index kc (0..15, 8-short chunks) stored at kc ^ (row&7);
// read side uses the same XOR (row&7 == l15&7 for all frag reads) -> 16 rows
// spread over 32 banks = 2 lanes/bank = conflict-free. Staging source addr
// carries the inverse permutation; LDS dest stays linear (DMA requirement).
// A staging: rows w*28..w*28+27 per wave -> uniform 7 DMAs/wave, no branch.
// Epilogue: acc -> per-wave LDS -> 16B coalesced stores (proven R3 code).
// FIRST:  act[(trial*100+row)][col] = softsign(A @ W1T^T + b1), bf16
// !FIRST: out[trial][row][col]      = A @ W2T^T + b2, fp32   (row < 100)
template <int KDIM, bool FIRST>
__global__ __launch_bounds__(256, 2) void gemm_kernel(
    const short* __restrict__ A,     // [B_*F_+pad][KDIM] bf16, K-contig
    const short* __restrict__ WT,    // [E][NCOLS][KDIM] bf16, K-contig
    const float* __restrict__ bias,  // [E][NCOLS]
    const int2* __restrict__ ttab,   // [B_] (trial, expert), expert-sorted
    short* __restrict__ actout,      // FIRST
    float* __restrict__ out)         // !FIRST
{
    constexpr int NCOLS = FIRST ? H_ : P_;
    constexpr int NI = 4;                        // n-frags per wave (BN=128)
    __shared__ short sbuf[(AROWS + 128) * BKL];  // 61440 B
    short* sA = sbuf;
    short* sB = sbuf + AROWS * BKL;
    const int slot = (blockIdx.x & 7) * 16 + (blockIdx.x >> 3);
    const int2 te = ttab[slot];
    const int trial = te.x, e = te.y;
    const int n0 = blockIdx.y * 128;
    const int t = threadIdx.x;
    const int lane = t & 63, w = t >> 6;
    const int wm = (w >> 1) * 64, wn = (w & 1) * 64;
    const int l15 = lane & 15, quad = lane >> 4;
    const int lsub = lane >> 4;               // staging sub-row 0..3
    const int lch = lane & 15;                // staging chunk index 0..15

    f32x4 acc[4][NI];
#pragma unroll
    for (int mi = 0; mi < 4; mi++)
#pragma unroll
        for (int ni = 0; ni < NI; ni++)
            acc[mi][ni] = (f32x4)(0.0f);

    float bv[NI];
#pragma unroll
    for (int ni = 0; ni < NI; ni++)
        bv[ni] = bias[(size_t)e * NCOLS + n0 + wn + ni * 16 + l15];

    const short* Ap = A + (size_t)trial * F_ * KDIM;
    const short* Bp = WT + ((size_t)e * NCOLS + n0) * KDIM;

    for (int k0 = 0; k0 < KDIM; k0 += BKL) {
        // ---- stage: one DMA instr covers 4 rows x 16 chunks (1 KB) ----
        // A: wave w covers rows w*28 .. w*28+27 (7 instrs, uniform)
#pragma unroll
        for (int i = 0; i < 7; i++) {
            const int rb = w * 28 + i * 4;
            const int row = rb + lsub;
            const int cg = lch ^ (row & 7);   // inverse-swizzled source chunk
            GLOAD16(Ap + (size_t)row * KDIM + k0 + cg * 8, &sA[rb * BKL]);
        }
        // B: wave w covers rows w*32 .. w*32+31 (8 instrs)
#pragma unroll
        for (int i = 0; i < 8; i++) {
            const int rb = w * 32 + i * 4;
            const int row = rb + lsub;
            const int cg = lch ^ (row & 7);
            GLOAD16(Bp + (size_t)row * KDIM + k0 + cg * 8, &sB[rb * BKL]);
        }
        __syncthreads();
        // ---- compute: 4 K-sub-steps of 32 ----
#pragma unroll
        for (int ks = 0; ks < 4; ks++) {
            const int sw = (((ks * 4 + quad) ^ (l15 & 7)) * 8);
            bf16x8 af, bfr[NI];
#pragma unroll
            for (int ni = 0; ni < NI; ni++)
                bfr[ni] = *(const bf16x8*)(&sB[(wn + ni * 16 + l15) * BKL + sw]);
#pragma unroll
            for (int mi = 0; mi < 4; mi++) {
                if (wm + mi * 16 < F_) {  // wave-uniform; indices constant
                    af = *(const bf16x8*)(&sA[(wm + mi * 16 + l15) * BKL + sw]);
#pragma unroll
                    for (int ni = 0; ni < NI; ni++)
                        acc[mi][ni] = __builtin_amdgcn_mfma_f32_16x16x32_bf16(af, bfr[ni], acc[mi][ni], 0, 0, 0);
                }
            }
        }
        __syncthreads();  // protects restage; last one protects epilogue
    }

    // ---- epilogue via per-wave LDS transpose -> coalesced 16B stores ----
    // C/D frag layout: col=lane&15, row=quad*4+reg.
    const int lr = lane >> 3;  // epilogue row-in-8 (rl&7 == lr)
    if constexpr (FIRST) {
        short* sW = sbuf + w * 4096;  // 64 rows x 64 bf16, chunk^=(row&7)
#pragma unroll
        for (int mi = 0; mi < 4; mi++) {
#pragma unroll
            for (int ni = 0; ni < 4; ni++) {
                const int cl = ni * 16 + l15;
#pragma unroll
                for (int r = 0; r < 4; r++) {
                    const int rl = mi * 16 + quad * 4 + r;  // 0..63
                    float v = acc[mi][ni][r] + bv[ni];
                    v = v / (1.0f + fabsf(v));  // softsign, SCALE=1
                    sW[rl * 64 + (((cl >> 3) ^ (rl & 7)) * 8) + (cl & 7)] = f2bf(v);
                }
            }
        }
#pragma unroll
        for (int i = 0; i < 8; i++) {
            const int rl = i * 8 + lr;        // 0..63 (rl&7 == lr)
            const int c = lane & 7;
            const bf16x8 v = *(const bf16x8*)(&sW[rl * 64 + ((c ^ lr) * 8)]);
            const int grow = wm + rl;
            if (grow < F_)
                *(bf16x8*)(&actout[((size_t)trial * F_ + grow) * H_ + n0 + wn + c * 8]) = v;
        }
    } else {
        float* fW = (float*)(sbuf) + w * 2048;  // 64 rows x 32 fp32 per wave
#pragma unroll
        for (int pass = 0; pass < NI; pass += 2) {
#pragma unroll
            for (int mi = 0; mi < 4; mi++) {
#pragma unroll
                for (int nj = 0; nj < 2; nj++) {
                    const int cl = nj * 16 + l15;   // 0..31
#pragma unroll
                    for (int r = 0; r < 4; r++) {
                        const int rl = mi * 16 + quad * 4 + r;  // 0..63
                        fW[rl * 32 + (((cl >> 2) ^ (rl & 7)) * 4) + (cl & 3)] =
                            acc[mi][pass + nj][r] + bv[pass + nj];
                    }
                }
            }
#pragma unroll
            for (int i = 0; i < 8; i++) {
                const int rl = i * 8 + lr;           // 0..63 (rl&7 == lr)
                const int c = lane & 7;              // 16B chunk, 32 cols = 8 chunks
                const float4 v = *(const float4*)(&fW[rl * 32 + ((c ^ lr) * 4)]);
                const int grow = wm + rl;
                if (grow < F_)
                    *(float4*)(&out[((size_t)trial * F_ + grow) * P_ + n0 + wn + pass * 16 + c * 4]) = v;
            }
            // per-wave private buffer; same-wave RAW across passes is ordered
            // by compiler-inserted lgkmcnt waits -> no barrier needed.
        }
    }
}

extern "C" void kernel_launch(void* const* d_in, const int* in_sizes, int n_in,
                              void* d_out, int out_size, void* d_ws, size_t ws_size,
                              hipStream_t stream) {
    const float* x  = (const float*)d_in[0];
    const int* eid  = (const int*)d_in[1];
    const float* W1 = (const float*)d_in[2];
    const float* b1 = (const float*)d_in[3];
    const float* W2 = (const float*)d_in[4];
    const float* b2 = (const float*)d_in[5];
    float* out = (float*)d_out;

    char* ws = (char*)d_ws;
    short* W1T = (short*)(ws);                          // [E][H][N]      8 MiB
    short* W2T = (short*)(ws + (size_t)(8u << 20));     // [E][P][H]      8 MiB
    short* act = (short*)(ws + (size_t)(16u << 20));    // [12800+128][H] ~26.5 MiB
    short* xbf = (short*)(ws + (size_t)(43u << 20));    // [12800+128][N] ~13.3 MiB
    int2* ttab = (int2*)(ws + (size_t)(57u << 20));     // [B_]

    prep<<<dim3(5249), 256, 0, stream>>>(x, W1, W2, eid, xbf, W1T, W2T, ttab);
    // gemm1: 1024 blocks (2/CU by LDS), BK=128 -> 4 K-steps, 60 DMAs/stage.
    gemm_kernel<N_, true><<<dim3(B_, H_ / 128), 256, 0, stream>>>(xbf, W1T, b1, ttab, act, nullptr);
    // gemm2: 512 blocks, BK=128 -> 8 K-steps.
    gemm_kernel<H_, false><<<dim3(B_, P_ / 128), 256, 0, stream>>>(act, W2T, b2, ttab, nullptr, out);
}

// Round 10
// 150.235 us; speedup vs baseline: 1.0589x; 1.0589x over previous
//
#include <hip/hip_runtime.h>
#include <hip/hip_bf16.h>

#define B_ 128
#define F_ 100
#define N_ 512
#define H_ 1024
#define P_ 512
#define E_ 8
#define BK 64
#define AROWS 112  // staged A rows (M=100 rounded to DMA granularity of 8)

typedef __attribute__((ext_vector_type(8))) short bf16x8;
typedef __attribute__((ext_vector_type(4))) float f32x4;

// async global->LDS DMA, 16B/lane, LDS dest = wave-uniform base + lane*16
#define GLOAD16(g, l) __builtin_amdgcn_global_load_lds(                      \
    (const __attribute__((address_space(1))) void*)(g),                      \
    (__attribute__((address_space(3))) void*)(l), 16, 0, 0)

static __device__ __forceinline__ short f2bf(float f) {
    __hip_bfloat16 h = __float2bfloat16(f);
    short s;
    __builtin_memcpy(&s, &h, sizeof(s));
    return s;
}

// ONE prep kernel, grid sections:
//   [0,3200)      convert x [B][F][N] fp32 -> xbf [12800][N] bf16 (linear)
//   [3200,4224)   transpose W1 [E][512][1024] -> W1T [E][1024][512] bf16
//   [4224,5248)   transpose W2 [E][1024][512] -> W2T [E][512][1024] bf16
//   5248          tile table sorted by expert (data stays in trial order)
__global__ __launch_bounds__(256) void prep(
    const float* __restrict__ x, const float* __restrict__ W1,
    const float* __restrict__ W2, const int* __restrict__ eid,
    short* __restrict__ xbf, short* __restrict__ W1T, short* __restrict__ W2T,
    int2* __restrict__ ttab) {
    __shared__ float tile[64][65];
    __shared__ int scnt[E_], sbase[E_];
    const int bx = blockIdx.x;
    const int t = threadIdx.x;
    if (bx < 3200) {  // ---- convert x ----
        const int g = bx * 256 + t;
        const int col = (g & 63) * 8;
        const int row = g >> 6;  // 0..12799
        const float* xp = x + (size_t)row * N_ + col;
        const float4 v0 = *(const float4*)(xp);
        const float4 v1 = *(const float4*)(xp + 4);
        union { short s[8]; uint4 u; } o;
        o.s[0] = f2bf(v0.x); o.s[1] = f2bf(v0.y);
        o.s[2] = f2bf(v0.z); o.s[3] = f2bf(v0.w);
        o.s[4] = f2bf(v1.x); o.s[5] = f2bf(v1.y);
        o.s[6] = f2bf(v1.z); o.s[7] = f2bf(v1.w);
        *(uint4*)(xbf + (size_t)row * N_ + col) = o.u;
    } else if (bx < 5248) {  // ---- weight transpose+convert ----
        const float* W; short* WT; int R, C, r0, c0, e;
        if (bx < 4224) {
            const int idx = bx - 3200;
            e = idx >> 7; const int i = idx & 127;
            W = W1; WT = W1T; R = N_; C = H_;
            r0 = (i >> 4) * 64; c0 = (i & 15) * 64;
        } else {
            const int idx = bx - 4224;
            e = idx >> 7; const int i = idx & 127;
            W = W2; WT = W2T; R = H_; C = P_;
            r0 = (i & 15) * 64; c0 = (i >> 4) * 64;
        }
        const float* Wp = W + (size_t)e * R * C;
        short* WTp = WT + (size_t)e * C * R;
        {
            const int c4 = (t & 15) * 4, r = t >> 4;
#pragma unroll
            for (int p = 0; p < 4; p++) {
                const int row = p * 16 + r;
                const float4 v = *(const float4*)(Wp + (size_t)(r0 + row) * C + c0 + c4);
                tile[row][c4 + 0] = v.x; tile[row][c4 + 1] = v.y;
                tile[row][c4 + 2] = v.z; tile[row][c4 + 3] = v.w;
            }
        }
        __syncthreads();
        {
            const int r8 = (t & 7) * 8, cl = t >> 3;
#pragma unroll
            for (int p = 0; p < 2; p++) {
                const int c = p * 32 + cl;
                union { short s[8]; uint4 u; } o;
#pragma unroll
                for (int j = 0; j < 8; j++) o.s[j] = f2bf(tile[r8 + j][c]);
                *(uint4*)(&WTp[(size_t)(c0 + c) * R + r0 + r8]) = o.u;
            }
        }
    } else {  // ---- tile-table sort (one block) ----
        if (t < E_) scnt[t] = 0;
        __syncthreads();
        int my_e = 0;
        if (t < B_) { my_e = eid[t]; atomicAdd(&scnt[my_e], 1); }
        __syncthreads();
        if (t == 0) {
            int s = 0;
            for (int i = 0; i < E_; i++) { sbase[i] = s; s += scnt[i]; }
        }
        __syncthreads();
        if (t < B_) {
            const int pos = atomicAdd(&sbase[my_e], 1);
            ttab[pos] = make_int2(t, my_e);
        }
    }
}

// ---- gemm1 WIDE: 128x256 tile, one trial per m-tile, BN=256 / NI=8 ----
// A staged ONCE per K-step for 256 output cols. 4 waves 2x2 (wave-tile
// 64x128), acc 4x8 f32x4, 2 blocks/CU. Single 46 KiB buffer, full-drain
// 2-phase. Same XOR swizzles as R3. Epilogue: two sequential 64-col passes
// over the proven 8 KiB/wave LDS scratch.
// act[(trial*100+row)][col] = softsign(xbf @ W1T^T + b1), bf16
__global__ __launch_bounds__(256, 2) void gemm1_wide(
    const short* __restrict__ A,     // [B_*F_+pad][N_] bf16, K-contig
    const short* __restrict__ WT,    // [E][H_][N_] bf16, K-contig
    const float* __restrict__ bias,  // [E][H_]
    const int2* __restrict__ ttab,   // [B_] (trial, expert), expert-sorted
    short* __restrict__ actout)
{
    constexpr int KDIM = N_;
    constexpr int NI = 8;            // n-frags per wave (BN=256, wn 128 wide)
    __shared__ short sbuf[(AROWS + 256) * BK];   // 47104 B
    short* sA = sbuf;
    short* sB = sbuf + AROWS * BK;
    const int slot = (blockIdx.x & 7) * 16 + (blockIdx.x >> 3);
    const int2 te = ttab[slot];
    const int trial = te.x, e = te.y;
    const int n0 = blockIdx.y * 256;
    const int t = threadIdx.x;
    const int lane = t & 63, w = t >> 6;
    const int wm = (w >> 1) * 64, wn = (w & 1) * 128;
    const int l15 = lane & 15, quad = lane >> 4;
    const int lr = lane >> 3;                 // staging row 0..7
    const int lc = (((lane & 7) ^ lr) * 8);   // XOR-swizzled col chunk

    f32x4 acc[4][NI];
#pragma unroll
    for (int mi = 0; mi < 4; mi++)
#pragma unroll
        for (int ni = 0; ni < NI; ni++)
            acc[mi][ni] = (f32x4)(0.0f);

    float bv[NI];
#pragma unroll
    for (int ni = 0; ni < NI; ni++)
        bv[ni] = bias[(size_t)e * H_ + n0 + wn + ni * 16 + l15];

    const short* Ap = A + (size_t)trial * F_ * KDIM;
    const short* Bp = WT + ((size_t)e * H_ + n0) * KDIM;

    for (int k0 = 0; k0 < KDIM; k0 += BK) {
        // stage: A 14 DMAs total (4/4/4/2 per wave); B 8 DMAs per wave
#pragma unroll
        for (int i = 0; i < 4; i++) {
            const int rb = w * 32 + i * 8;
            if (rb < AROWS)  // wave-uniform; rows 112..127 never read
                GLOAD16(Ap + (size_t)(rb + lr) * KDIM + k0 + lc, &sA[rb * BK]);
        }
#pragma unroll
        for (int i = 0; i < 8; i++) {
            const int rb = w * 64 + i * 8;   // 4 waves cover 256 rows
            GLOAD16(Bp + (size_t)(rb + lr) * KDIM + k0 + lc, &sB[rb * BK]);
        }
        __syncthreads();
#pragma unroll
        for (int ks = 0; ks < 2; ks++) {
            const int sw = (((ks * 4 + quad) ^ (l15 & 7)) * 8);
            bf16x8 af, bfr[NI];
#pragma unroll
            for (int ni = 0; ni < NI; ni++)
                bfr[ni] = *(const bf16x8*)(&sB[(wn + ni * 16 + l15) * BK + sw]);
#pragma unroll
            for (int mi = 0; mi < 4; mi++) {
                if (wm + mi * 16 < F_) {  // wave-uniform; indices constant
                    af = *(const bf16x8*)(&sA[(wm + mi * 16 + l15) * BK + sw]);
#pragma unroll
                    for (int ni = 0; ni < NI; ni++)
                        acc[mi][ni] = __builtin_amdgcn_mfma_f32_16x16x32_bf16(af, bfr[ni], acc[mi][ni], 0, 0, 0);
                }
            }
        }
        __syncthreads();  // protects restage; last one protects epilogue
    }

    // ---- epilogue: two sequential 64-col passes, 8 KiB/wave scratch ----
    // C/D frag layout: col=lane&15, row=quad*4+reg.
    short* sW = sbuf + w * 4096;  // 64 rows x 64 bf16 per wave per pass
#pragma unroll
    for (int pass = 0; pass < 2; pass++) {
#pragma unroll
        for (int mi = 0; mi < 4; mi++) {
#pragma unroll
            for (int nj = 0; nj < 4; nj++) {
                const int ni = pass * 4 + nj;
                const int cl = nj * 16 + l15;
#pragma unroll
                for (int r = 0; r < 4; r++) {
                    const int rl = mi * 16 + quad * 4 + r;  // 0..63
                    float v = acc[mi][ni][r] + bv[ni];
                    v = v / (1.0f + fabsf(v));  // softsign, SCALE=1
                    sW[rl * 64 + (((cl >> 3) ^ (rl & 7)) * 8) + (cl & 7)] = f2bf(v);
                }
            }
        }
#pragma unroll
        for (int i = 0; i < 8; i++) {
            const int rl = i * 8 + lr;        // 0..63 (rl&7 == lr)
            const int c = lane & 7;
            const bf16x8 v = *(const bf16x8*)(&sW[rl * 64 + ((c ^ lr) * 8)]);
            const int grow = wm + rl;
            if (grow < F_)
                *(bf16x8*)(&actout[((size_t)trial * F_ + grow) * H_ + n0 + wn + pass * 64 + c * 8]) = v;
        }
        // per-wave private scratch; same-wave DS ops are ordered -> the
        // pass-1 writes can't pass the pass-0 reads.
    }
}

// ---- gemm2: R3's counted-vmcnt dbuf kernel (measured-best config) ----
// 128x128 tile, BN=128, 60 KiB double-buffer, counted s_waitcnt vmcnt(8/6)
// + raw s_barrier before compute (next-tile DMAs stay in flight), plain
// s_barrier after. 2 blocks/CU. Epilogue: NI/2 passes fp32, 16B stores.
// out[trial][row][col] = act @ W2T^T + b2, fp32 (row < 100)
template <int KDIM, int BN_>
__global__ __launch_bounds__(256, 2) void gemm2_kernel(
    const short* __restrict__ A,     // [B_*F_+pad][KDIM] bf16, K-contig
    const short* __restrict__ WT,    // [E][P_][KDIM] bf16, K-contig
    const float* __restrict__ bias,  // [E][P_]
    const int2* __restrict__ ttab,   // [B_] (trial, expert), expert-sorted
    float* __restrict__ out)
{
    constexpr int NCOLS = P_;
    constexpr int NI = BN_ / 32;                   // n-frags per wave
    constexpr int STAGE1 = (AROWS + BN_) * BK;     // shorts per staging buffer
    constexpr int EPI_SH = 4 * 4096;               // 4 waves x 8 KiB
    constexpr int SBUF_SH = (2 * STAGE1 > EPI_SH) ? 2 * STAGE1 : EPI_SH;
    __shared__ short sbuf[SBUF_SH];
    const int slot = (blockIdx.x & 7) * 16 + (blockIdx.x >> 3);
    const int2 te = ttab[slot];
    const int trial = te.x, e = te.y;
    const int n0 = blockIdx.y * BN_;
    const int t = threadIdx.x;
    const int lane = t & 63, w = t >> 6;
    const int wm = (w >> 1) * 64, wn = (w & 1) * (BN_ / 2);
    const int l15 = lane & 15, quad = lane >> 4;
    const int lr = lane >> 3;                 // staging row 0..7
    const int lc = (((lane & 7) ^ lr) * 8);   // XOR-swizzled col chunk

    f32x4 acc[4][NI];
#pragma unroll
    for (int mi = 0; mi < 4; mi++)
#pragma unroll
        for (int ni = 0; ni < NI; ni++)
            acc[mi][ni] = (f32x4)(0.0f);

    float bv[NI];
#pragma unroll
    for (int ni = 0; ni < NI; ni++)
        bv[ni] = bias[(size_t)e * NCOLS + n0 + wn + ni * 16 + l15];

    const short* Ap = A + (size_t)trial * F_ * KDIM;
    const short* Bp = WT + ((size_t)e * NCOLS + n0) * KDIM;

    auto stage = [&](int k0, short* sb) {
        short* sA = sb;
        short* sB = sb + AROWS * BK;
#pragma unroll
        for (int i = 0; i < 4; i++) {
            const int rb = w * 32 + i * 8;
            if (rb < AROWS)  // wave-uniform; waves 0-2: 4 DMAs, wave 3: 2
                GLOAD16(Ap + (size_t)(rb + lr) * KDIM + k0 + lc, &sA[rb * BK]);
        }
#pragma unroll
        for (int i = 0; i < NI; i++) {
            const int rb = w * (BN_ / 4) + i * 8;
            GLOAD16(Bp + (size_t)(rb + lr) * KDIM + k0 + lc, &sB[rb * BK]);
        }
    };

    auto compute = [&](const short* sb) {
        const short* sA = sb;
        const short* sB = sb + AROWS * BK;
#pragma unroll
        for (int ks = 0; ks < 2; ks++) {
            const int sw = (((ks * 4 + quad) ^ (l15 & 7)) * 8);
            bf16x8 af, bfr[NI];
#pragma unroll
            for (int ni = 0; ni < NI; ni++)
                bfr[ni] = *(const bf16x8*)(&sB[(wn + ni * 16 + l15) * BK + sw]);
#pragma unroll
            for (int mi = 0; mi < 4; mi++) {
                if (wm + mi * 16 < F_) {  // wave-uniform; indices constant
                    af = *(const bf16x8*)(&sA[(wm + mi * 16 + l15) * BK + sw]);
#pragma unroll
                    for (int ni = 0; ni < NI; ni++)
                        acc[mi][ni] = __builtin_amdgcn_mfma_f32_16x16x32_bf16(af, bfr[ni], acc[mi][ni], 0, 0, 0);
                }
            }
        }
    };

    auto wait_prev_and_bar = [&]() {  // retire exactly the PREVIOUS stage
        if (w < 3) asm volatile("s_waitcnt vmcnt(8)" ::: "memory");
        else       asm volatile("s_waitcnt vmcnt(6)" ::: "memory");
        __builtin_amdgcn_s_barrier();
        __builtin_amdgcn_sched_barrier(0);
    };
    auto bar = [&]() {  // plain exec barrier, no drain
        __builtin_amdgcn_sched_barrier(0);
        __builtin_amdgcn_s_barrier();
        __builtin_amdgcn_sched_barrier(0);
    };

    short* b0 = sbuf;
    short* b1 = sbuf + STAGE1;

    stage(0, b0);
    for (int k0 = 0; k0 < KDIM - 2 * BK; k0 += 2 * BK) {
        stage(k0 + BK, b1);
        wait_prev_and_bar();        // b0 ready; b1 loads remain in flight
        compute(b0);
        bar();                      // b0 reads done -> safe to restage b0
        stage(k0 + 2 * BK, b0);
        wait_prev_and_bar();        // b1 ready
        compute(b1);
        bar();
    }
    stage(KDIM - BK, b1);
    wait_prev_and_bar();
    compute(b0);
    bar();
    asm volatile("s_waitcnt vmcnt(0)" ::: "memory");
    __builtin_amdgcn_s_barrier();
    __builtin_amdgcn_sched_barrier(0);
    compute(b1);
    bar();                          // protect sbuf before epilogue reuse

    // ---- fp32 epilogue: NI/2 passes of 32 cols, 8 KiB/wave scratch ----
    float* fW = (float*)(sbuf) + w * 2048;  // 64 rows x 32 fp32 per wave
#pragma unroll
    for (int pass = 0; pass < NI; pass += 2) {
#pragma unroll
        for (int mi = 0; mi < 4; mi++) {
#pragma unroll
            for (int nj = 0; nj < 2; nj++) {
                const int cl = nj * 16 + l15;   // 0..31
#pragma unroll
                for (int r = 0; r < 4; r++) {
                    const int rl = mi * 16 + quad * 4 + r;  // 0..63
                    fW[rl * 32 + (((cl >> 2) ^ (rl & 7)) * 4) + (cl & 3)] =
                        acc[mi][pass + nj][r] + bv[pass + nj];
                }
            }
        }
#pragma unroll
        for (int i = 0; i < 8; i++) {
            const int rl = i * 8 + lr;           // 0..63 (rl&7 == lr)
            const int c = lane & 7;              // 16B chunk, 32 cols = 8 chunks
            const float4 v = *(const float4*)(&fW[rl * 32 + ((c ^ lr) * 4)]);
            const int grow = wm + rl;
            if (grow < F_)
                *(float4*)(&out[((size_t)trial * F_ + grow) * P_ + n0 + wn + pass * 16 + c * 4]) = v;
        }
    }
}

extern "C" void kernel_launch(void* const* d_in, const int* in_sizes, int n_in,
                              void* d_out, int out_size, void* d_ws, size_t ws_size,
                              hipStream_t stream) {
    const float* x  = (const float*)d_in[0];
    const int* eid  = (const int*)d_in[1];
    const float* W1 = (const float*)d_in[2];
    const float* b1 = (const float*)d_in[3];
    const float* W2 = (const float*)d_in[4];
    const float* b2 = (const float*)d_in[5];
    float* out = (float*)d_out;

    char* ws = (char*)d_ws;
    short* W1T = (short*)(ws);                          // [E][H][N]      8 MiB
    short* W2T = (short*)(ws + (size_t)(8u << 20));     // [E][P][H]      8 MiB
    short* act = (short*)(ws + (size_t)(16u << 20));    // [12800+128][H] ~26.5 MiB
    short* xbf = (short*)(ws + (size_t)(43u << 20));    // [12800+128][N] ~13.3 MiB
    int2* ttab = (int2*)(ws + (size_t)(57u << 20));     // [B_]

    prep<<<dim3(5249), 256, 0, stream>>>(x, W1, W2, eid, xbf, W1T, W2T, ttab);
    // gemm1: BN=256 wide tile, 512 blocks (2/CU), A staged 4x not 8x.
    gemm1_wide<<<dim3(B_, H_ / 256), 256, 0, stream>>>(xbf, W1T, b1, ttab, act);
    // gemm2: R3 config (counted-vmcnt dbuf, BN=128, 512 blocks).
    gemm2_kernel<H_, 128><<<dim3(B_, P_ / 128), 256, 0, stream>>>(act, W2T, b2, ttab, out);
}